// Round 3
// baseline (200.871 us; speedup 1.0000x reference)
//
#include <hip/hip_runtime.h>
#include <hip/hip_bf16.h>
#include <cstdint>
#include <cstddef>

constexpr int Bn = 8;
constexpr int Nn = 2048;
constexpr int Dn = 128;

typedef __bf16 bf16x8 __attribute__((ext_vector_type(8)));
typedef float f32x4 __attribute__((ext_vector_type(4)));

#define AS1 __attribute__((address_space(1)))
#define AS3 __attribute__((address_space(3)))

static __device__ __forceinline__ void gl_lds16(const void* g, void* l) {
  __builtin_amdgcn_global_load_lds((AS1 const void*)g, (AS3 void*)l, 16, 0, 0);
}

// -----------------------------------------------------------------------------
// Kernel 0: pack adj (int32 0/1, N*N) into a bitmask via __ballot.
// 16384 blocks x 256 thr; each wave packs 64 adjacent elements -> one u64.
// -----------------------------------------------------------------------------
__global__ __launch_bounds__(256) void gat_k0(
    const int* __restrict__ adj, unsigned long long* __restrict__ mask64) {
  const int t = threadIdx.x;
  const size_t g = (size_t)blockIdx.x * 256 + t;
  int v = adj[g];
  unsigned long long bal = __ballot(v > 0);
  if ((t & 63) == 0) mask64[g >> 6] = bal;
}

// -----------------------------------------------------------------------------
// Kernel 1: h = x@W (fp32), s1 = h@a1, s2 = h@a2, hT bf16 [B][D][N].
// 512 blocks x 256 thr; 32 rows/block; thread tile 2 rows x 8 cols.
// -----------------------------------------------------------------------------
__global__ __launch_bounds__(256) void gat_k1(
    const float* __restrict__ x, const float* __restrict__ W,
    const float* __restrict__ a_vec,
    __bf16* __restrict__ hT, float* __restrict__ s1, float* __restrict__ s2) {
  __shared__ __align__(16) float Wl[64 * 144];
  __shared__ __align__(16) float xL[32 * 132];

  const int t = threadIdx.x;
  const int r0 = blockIdx.x * 32;
  const int b = r0 >> 11;
  const int n0 = r0 & (Nn - 1);
  const int rp = (t >> 4) << 1;
  const int c0 = (t & 15) << 3;
  const int c0p = c0 + ((c0 >> 5) << 2);

  float acc[2][8];
#pragma unroll
  for (int r = 0; r < 2; ++r)
#pragma unroll
    for (int c = 0; c < 8; ++c) acc[r][c] = 0.f;

#pragma unroll
  for (int it = 0; it < 4; ++it) {
    int idx = t + (it << 8);
    int rr = idx >> 5, kc = (idx & 31) << 2;
    *(float4*)(xL + rr * 132 + kc) = *(const float4*)(x + (size_t)(r0 + rr) * Dn + kc);
  }

  for (int ph = 0; ph < 2; ++ph) {
    if (ph) __syncthreads();
#pragma unroll
    for (int it = 0; it < 8; ++it) {
      int idx = t + (it << 8);
      int kk = idx >> 5, c4 = (idx & 31) << 2;
      int dsto = kk * 144 + c4 + ((c4 >> 5) << 2);
      *(float4*)(Wl + dsto) = *(const float4*)(W + (size_t)((ph << 6) + kk) * Dn + c4);
    }
    __syncthreads();
    const float* xrow = xL + rp * 132 + (ph << 6);
    for (int k = 0; k < 64; ++k) {
      float xa0 = xrow[k];
      float xa1 = xrow[132 + k];
      float4 w0 = *(const float4*)(Wl + k * 144 + c0p);
      float4 w1 = *(const float4*)(Wl + k * 144 + c0p + 4);
      float ws[8] = {w0.x, w0.y, w0.z, w0.w, w1.x, w1.y, w1.z, w1.w};
#pragma unroll
      for (int c = 0; c < 8; ++c) {
        acc[0][c] = fmaf(xa0, ws[c], acc[0][c]);
        acc[1][c] = fmaf(xa1, ws[c], acc[1][c]);
      }
    }
  }

  float q1[2] = {0.f, 0.f}, q2[2] = {0.f, 0.f};
#pragma unroll
  for (int c = 0; c < 8; ++c) {
    float a1c = a_vec[c0 + c];
    float a2c = a_vec[Dn + c0 + c];
    q1[0] = fmaf(acc[0][c], a1c, q1[0]);
    q1[1] = fmaf(acc[1][c], a1c, q1[1]);
    q2[0] = fmaf(acc[0][c], a2c, q2[0]);
    q2[1] = fmaf(acc[1][c], a2c, q2[1]);
  }
#pragma unroll
  for (int d = 1; d < 16; d <<= 1) {
    q1[0] += __shfl_xor(q1[0], d);
    q1[1] += __shfl_xor(q1[1], d);
    q2[0] += __shfl_xor(q2[0], d);
    q2[1] += __shfl_xor(q2[1], d);
  }
  if ((t & 15) == 0) {
    s1[b * Nn + n0 + rp] = q1[0];
    s1[b * Nn + n0 + rp + 1] = q1[1];
    s2[b * Nn + n0 + rp] = q2[0];
    s2[b * Nn + n0 + rp + 1] = q2[1];
  }

#pragma unroll
  for (int c = 0; c < 8; ++c) {
    union { __bf16 h[2]; uint32_t u; } pk;
    pk.h[0] = (__bf16)acc[0][c];
    pk.h[1] = (__bf16)acc[1][c];
    *(uint32_t*)(hT + (size_t)(b * Dn + c0 + c) * Nn + n0 + rp) = pk.u;
  }
}

// -----------------------------------------------------------------------------
// Kernel 2: per (b, 32 i-rows): softmax denom, alpha, out via MFMA.
// 512 blocks x 512 thr. Block g -> b = g&7 (XCD-pinned batch), i0 = (g>>3)*32.
// adj consumed as bitmask (u32 words, 64/row).
// -----------------------------------------------------------------------------
__global__ __launch_bounds__(512) void gat_k2(
    const uint32_t* __restrict__ mask, const __bf16* __restrict__ hT,
    const float* __restrict__ s1, const float* __restrict__ s2,
    float* __restrict__ out, float* __restrict__ alpha) {
  __shared__ __align__(16) float sj[Nn];            // 8 KB
  __shared__ float siv[32], invl[32];
  __shared__ __align__(16) __bf16 Pl[2][32 * 72];   // 9 KB
  __shared__ __align__(16) __bf16 hl[2][128 * 64];  // 32 KB, swizzled

  const int t = threadIdx.x;
  const int b = blockIdx.x & 7;                 // XCD-pinned batch
  const int i0 = (blockIdx.x >> 3) << 5;
  const int w = t >> 6, lane = t & 63;
  const int ii = t >> 4, sub = t & 15;
  const int lrow = lane >> 3, ccs = lane & 7;
  const __bf16* __restrict__ hTb = hT + (size_t)b * Dn * Nn;

  // prologue: prefetch j-tile 0 into hl[0]
#pragma unroll
  for (int inst = 0; inst < 2; ++inst) {
    int row = (w << 4) + (inst << 3) + lrow;
    gl_lds16(hTb + (size_t)row * Nn + ((ccs ^ lrow) << 3),
             &hl[0][((w << 4) + (inst << 3)) << 6]);
  }

  *(float4*)(sj + (t << 2)) = *(const float4*)(s2 + b * Nn + (t << 2));
  if (t < 32) siv[t] = s1[b * Nn + i0 + t];
  __syncthreads();

  const int i = i0 + ii;
  const uint32_t* __restrict__ mrow = mask + ((size_t)i << 6);  // 64 words/row
  const float si = siv[ii];

  // pass 1: l_i = sum_j bit * exp(lrelu(si+sj)); thread covers j = cc*64 + sub*4
  float l = 0.f;
  const int wofs = sub >> 3;          // which of the 2 words in a 64-j chunk
  const int bsh = (sub & 7) << 2;     // bit base within word
  for (int cc = 0; cc < 32; ++cc) {
    int j = (cc << 6) + (sub << 2);
    uint32_t mw = mrow[(cc << 1) + wofs];
    float4 sv = *(const float4*)(sj + j);
    float e;
    e = si + sv.x; e = fmaxf(e, 0.2f * e); l += ((mw >> (bsh + 0)) & 1u) ? __expf(e) : 0.f;
    e = si + sv.y; e = fmaxf(e, 0.2f * e); l += ((mw >> (bsh + 1)) & 1u) ? __expf(e) : 0.f;
    e = si + sv.z; e = fmaxf(e, 0.2f * e); l += ((mw >> (bsh + 2)) & 1u) ? __expf(e) : 0.f;
    e = si + sv.w; e = fmaxf(e, 0.2f * e); l += ((mw >> (bsh + 3)) & 1u) ? __expf(e) : 0.f;
  }
  l += __shfl_xor(l, 1);
  l += __shfl_xor(l, 2);
  l += __shfl_xor(l, 4);
  l += __shfl_xor(l, 8);
  if (sub == 0) invl[ii] = 1.f / l;
  __syncthreads();
  const float il = invl[ii];

  const int iw = (w & 1) << 4;
  const int nd0 = (w >> 1) << 5;
  const int q16 = lane >> 4, m16 = lane & 15;
  f32x4 acc0 = {0.f, 0.f, 0.f, 0.f}, acc1 = {0.f, 0.f, 0.f, 0.f};
  float* __restrict__ arow = alpha + ((size_t)(b * Nn + i) << 11);

  for (int jt = 0; jt < 32; ++jt) {
    const int buf = jt & 1;
    const int j0 = jt << 6;
    {
      int j = j0 + (sub << 2);
      uint32_t mw = mrow[(j0 >> 5) + wofs];
      float4 sv = *(const float4*)(sj + j);
      float e0 = si + sv.x; e0 = fmaxf(e0, 0.2f * e0);
      float e1 = si + sv.y; e1 = fmaxf(e1, 0.2f * e1);
      float e2 = si + sv.z; e2 = fmaxf(e2, 0.2f * e2);
      float e3 = si + sv.w; e3 = fmaxf(e3, 0.2f * e3);
      float a0 = ((mw >> (bsh + 0)) & 1u) ? __expf(e0) * il : 0.f;
      float a1 = ((mw >> (bsh + 1)) & 1u) ? __expf(e1) * il : 0.f;
      float a2 = ((mw >> (bsh + 2)) & 1u) ? __expf(e2) * il : 0.f;
      float a3 = ((mw >> (bsh + 3)) & 1u) ? __expf(e3) * il : 0.f;
      *(float4*)(arow + j) = make_float4(a0, a1, a2, a3);
      union { __bf16 h[4]; uint2 u; } pk;
      pk.h[0] = (__bf16)a0; pk.h[1] = (__bf16)a1;
      pk.h[2] = (__bf16)a2; pk.h[3] = (__bf16)a3;
      *(uint2*)(&Pl[buf][ii * 72 + (sub << 2)]) = pk.u;
    }
    __syncthreads();  // hl[buf] drained; Pl[buf] visible; prev MFMA reads done
    if (jt < 31) {
      int jn = j0 + 64;
#pragma unroll
      for (int inst = 0; inst < 2; ++inst) {
        int row = (w << 4) + (inst << 3) + lrow;
        gl_lds16(hTb + (size_t)row * Nn + jn + ((ccs ^ lrow) << 3),
                 &hl[buf ^ 1][((w << 4) + (inst << 3)) << 6]);
      }
    }
#pragma unroll
    for (int ks = 0; ks < 2; ++ks) {
      bf16x8 af = *(const bf16x8*)(&Pl[buf][(iw + m16) * 72 + (ks << 5) + (q16 << 3)]);
      {
        int d = nd0 + m16;
        int phys = ((ks << 2) + q16) ^ (d & 7);
        bf16x8 bv = *(const bf16x8*)(&hl[buf][(d << 6) + (phys << 3)]);
        acc0 = __builtin_amdgcn_mfma_f32_16x16x32_bf16(af, bv, acc0, 0, 0, 0);
      }
      {
        int d = nd0 + 16 + m16;
        int phys = ((ks << 2) + q16) ^ (d & 7);
        bf16x8 bv = *(const bf16x8*)(&hl[buf][(d << 6) + (phys << 3)]);
        acc1 = __builtin_amdgcn_mfma_f32_16x16x32_bf16(af, bv, acc1, 0, 0, 0);
      }
    }
  }

#pragma unroll
  for (int nb = 0; nb < 2; ++nb) {
    f32x4 a = nb ? acc1 : acc0;
    int d = nd0 + (nb << 4) + m16;
#pragma unroll
    for (int r = 0; r < 4; ++r) {
      int irow = i0 + iw + (q16 << 2) + r;
      out[((size_t)(b * Nn + irow) << 7) + d] = a[r];
    }
  }
}

extern "C" void kernel_launch(void* const* d_in, const int* in_sizes, int n_in,
                              void* d_out, int out_size, void* d_ws, size_t ws_size,
                              hipStream_t stream) {
  const float* x = (const float*)d_in[0];
  const int* adj = (const int*)d_in[1];
  const float* W = (const float*)d_in[2];
  const float* a_vec = (const float*)d_in[3];

  float* out = (float*)d_out;
  float* alpha = out + (size_t)Bn * Nn * Dn;

  char* ws = (char*)d_ws;
  __bf16* hT = (__bf16*)ws;                               // 4 MiB
  float* s1 = (float*)(ws + (size_t)Bn * Dn * Nn * 2);    // B*N fp32
  float* s2 = s1 + (size_t)Bn * Nn;                       // B*N fp32
  unsigned long long* mask64 = (unsigned long long*)(s2 + (size_t)Bn * Nn);  // 512 KiB

  gat_k0<<<(Nn * Nn) / 256, 256, 0, stream>>>(adj, mask64);
  gat_k1<<<512, 256, 0, stream>>>(x, W, a_vec, hT, s1, s2);
  gat_k2<<<512, 512, 0, stream>>>((const uint32_t*)mask64, hT, s1, s2, out, alpha);
}